// Round 3
// baseline (170.452 us; speedup 1.0000x reference)
//
#include <hip/hip_runtime.h>
#include <stdint.h>

#define NB    1024   // batch
#define NUM   512    // nodes
#define HD    64     // hidden dim
#define NE    4096   // edges
#define NEP   4608   // padded edge capacity (each column padded to even count)
#define MAIN  10     // softmax segment

typedef _Float16 hlf;
typedef __attribute__((ext_vector_type(2))) _Float16 hlf2;
typedef __attribute__((ext_vector_type(8))) _Float16 hlf8;
typedef __attribute__((ext_vector_type(4))) float f32x4;

__device__ __forceinline__ unsigned short f2h(float f) {
    hlf v = (hlf)f;
    return __builtin_bit_cast(unsigned short, v);
}

// ---------------------------------------------------------------------------
// Prep: block 0 builds degree-sorted, even-padded CSR (packed rank
// descriptors desc[r] = e0 | col<<13 | pdeg<<22) via wave-shfl scans;
// blocks 1..72 cast E1 = emb@W1 and W2T = W2^T to f16.
// Edge pack: epk = (row << 23) | f16(norm)  -> row*128 = byte offset in hi16.
// ---------------------------------------------------------------------------
__global__ __launch_bounds__(512) void prep_all(
    const int* __restrict__ erow, const int* __restrict__ ecol,
    const float* __restrict__ emb, const float* __restrict__ W1,
    const float* __restrict__ W2,
    unsigned* __restrict__ desc, int* __restrict__ epk,
    short* __restrict__ E1, short* __restrict__ W2T)
{
    const int t = threadIdx.x;
    if (blockIdx.x != 0) {
        int g = (blockIdx.x - 1) * 512 + t;     // 72 x 512 = 36864
        if (g < NUM * HD) {
            int node = g >> 6, dim = g & 63;
            float acc = 0.0f;
            #pragma unroll
            for (int k = 0; k < HD; ++k) acc += emb[node * HD + k] * W1[k * HD + dim];
            E1[g] = (short)f2h(acc);
        } else if (g < NUM * HD + HD * HD) {
            int j = g - NUM * HD;
            int dout = j >> 6, din = j & 63;
            W2T[j] = (short)f2h(W2[din * HD + dout]);
        }
        return;
    }

    __shared__ int   sdeg[NUM];     // degree -> bin cursor -> edge cursor
    __shared__ int   aux[NUM];      // histogram scan -> rank starts
    __shared__ float sdv[NUM];
    __shared__ int   rnk[NUM];
    __shared__ int   rdg[NUM];      // padded degree by rank
    __shared__ int   scol[NUM];     // original col by rank
    __shared__ int   wsum[8];

    const int lane = t & 63, wv = t >> 6;

    sdeg[t] = 0; aux[t] = 0;
    __syncthreads();
    for (int e = t; e < NE; e += 512) atomicAdd(&sdeg[ecol[e]], 1);
    __syncthreads();
    const int deg  = sdeg[t];
    const int pdeg = (deg + 1) & ~1;            // pad to even
    const int dbin = deg < NUM ? deg : NUM - 1;
    sdv[t] = deg > 0 ? rsqrtf((float)deg) : 0.0f;
    atomicAdd(&aux[dbin], 1);
    __syncthreads();
    // scan histogram (shfl)
    {
        int v = aux[t];
        #pragma unroll
        for (int ofs = 1; ofs < 64; ofs <<= 1) {
            int sh = __shfl_up(v, ofs, 64);
            if (lane >= ofs) v += sh;
        }
        if (lane == 63) wsum[wv] = v;
        __syncthreads();
        if (t == 0) {
            int s = 0;
            #pragma unroll
            for (int w = 0; w < 8; ++w) { int tmp = wsum[w]; wsum[w] = s; s += tmp; }
        }
        __syncthreads();
        int inc = v + wsum[wv];
        aux[t]  = inc;                          // inclusive histogram scan
        __syncthreads();
        sdeg[t] = (t == 0) ? 0 : aux[t - 1];    // bin cursors (exclusive)
        __syncthreads();
    }
    {
        int r = atomicAdd(&sdeg[dbin], 1);      // degree-sorted rank
        rnk[t] = r;
        rdg[r] = pdeg;
        scol[r] = t;
    }
    __syncthreads();
    // scan padded degrees by rank -> rank CSR (all-even offsets) + descriptors
    {
        int dv = rdg[t], v = dv;
        #pragma unroll
        for (int ofs = 1; ofs < 64; ofs <<= 1) {
            int sh = __shfl_up(v, ofs, 64);
            if (lane >= ofs) v += sh;
        }
        if (lane == 63) wsum[wv] = v;
        __syncthreads();
        if (t == 0) {
            int s = 0;
            #pragma unroll
            for (int w = 0; w < 8; ++w) { int tmp = wsum[w]; wsum[w] = s; s += tmp; }
        }
        __syncthreads();
        int inc  = v + wsum[wv];
        int excl = inc - dv;
        desc[t] = (unsigned)excl | ((unsigned)scol[t] << 13) | ((unsigned)dv << 22);
        aux[t] = excl;                          // rank start
        __syncthreads();
    }
    sdeg[t] = aux[rnk[t]];                      // per-ORIGINAL-col edge cursor
    __syncthreads();
    for (int i = t; i < NEP; i += 512) epk[i] = 0;   // zero pads
    __syncthreads();
    for (int e = t; e < NE; e += 512) {
        int c = ecol[e], rr = erow[e];
        int p = atomicAdd(&sdeg[c], 1);
        unsigned ns = (unsigned)f2h(sdv[rr] * sdv[c]);
        epk[p] = (rr << 23) | (int)ns;          // hi16 = row*128 (byte offset)
    }
}

// ---------------------------------------------------------------------------
// Body: one block (1024 thr, 16 waves) per batch element; 2 blocks/CU.
// Uses S@(h@W) = (S@h)@W to defer both dense matmuls past the aggregations:
//   SpMM1: h1 = relu(S@(x*E1) + b1)       gather E1 from L2, scale n*x (LDS xe)
//   SpMM2: agg2 = S@h1                    gather h1 from LDS
//   MFMA : z2 = agg2@W2 + b2; t = relu(z2).W3   -> tv
//   SpMM3: logits = S@tv + b3; softmax/sigmoid
// ---------------------------------------------------------------------------
__global__ __launch_bounds__(1024, 8) void gcn_body(
    const float* __restrict__ x, const hlf* __restrict__ E1,
    const hlf* __restrict__ W2T,
    const float* __restrict__ b1, const float* __restrict__ b2,
    const float* __restrict__ W3, const float* __restrict__ b3,
    const unsigned* __restrict__ descg, const int* __restrict__ epkg,
    float* __restrict__ out)
{
    __shared__ hlf   H[NUM * HD];      // 65536 B: h1, then A2 (swizzled), then slog/sred
    __shared__ float aux[NUM];         // 2048 B: x, then tv
    __shared__ hlf   xe[NEP];          // 9216 B: per-edge n*x[row] (layer-1 scale)

    float* slog = (float*)H;           // overlays H after MFMA phase
    float* sred = ((float*)H) + NUM;

    const int t     = threadIdx.x;
    const int b     = blockIdx.x;
    const int lane  = t & 63;
    const int wave  = t >> 6;          // 0..15
    const int q     = lane >> 4;
    const int l15   = lane & 15;
    const int grp   = lane >> 3;       // column slot within wave
    const int l7    = lane & 7;
    const int dbase = l7 * 8;          // this lane's 8-dim strip

    // ---- stage x, build per-edge layer-1 scales xe = n * x[row]
    if (t < NUM) aux[t] = x[b * NUM + t];
    __syncthreads();
    for (int i = t; i < NEP; i += 1024) {
        unsigned pe = (unsigned)epkg[i];
        float nf = (float)__builtin_bit_cast(hlf2, pe)[0];
        xe[i] = (hlf)(nf * aux[pe >> 23]);      // pads: n=0 -> xe=0
    }

    // per-lane bias strip (layer 1)
    float b1v[8];
    {
        f32x4 u0 = *(const f32x4*)&b1[dbase], u1 = *(const f32x4*)&b1[dbase + 4];
        #pragma unroll
        for (int j = 0; j < 4; ++j) { b1v[j] = u0[j]; b1v[j + 4] = u1[j]; }
    }
    __syncthreads();

// 8 f16->f32 mixed FMAs, f32 accumulate; sc is an f16 scale
#define MAC8(hv, sc) {                                                        \
        const hlf2 p0 = __builtin_bit_cast(hlf2, (hv).x);                     \
        const hlf2 p1 = __builtin_bit_cast(hlf2, (hv).y);                     \
        const hlf2 p2 = __builtin_bit_cast(hlf2, (hv).z);                     \
        const hlf2 p3 = __builtin_bit_cast(hlf2, (hv).w);                     \
        a[0] = fmaf((float)p0[0], (float)(sc), a[0]);                         \
        a[1] = fmaf((float)p0[1], (float)(sc), a[1]);                         \
        a[2] = fmaf((float)p1[0], (float)(sc), a[2]);                         \
        a[3] = fmaf((float)p1[1], (float)(sc), a[3]);                         \
        a[4] = fmaf((float)p2[0], (float)(sc), a[4]);                         \
        a[5] = fmaf((float)p2[1], (float)(sc), a[5]);                         \
        a[6] = fmaf((float)p3[0], (float)(sc), a[6]);                         \
        a[7] = fmaf((float)p3[1], (float)(sc), a[7]); }

    // ---- SpMM1: h1 = relu(S @ (x*E1) + b1) -> H[c][d]; gather E1 from L2
    {
        const char* E1b = (const char*)E1 + dbase * 2;
        #pragma unroll 1
        for (int set = 0; set < 4; ++set) {
            int r = set * 128 + wave * 8 + grp;
            unsigned d = descg[r];
            int e0 = d & 8191, c = (d >> 13) & 511, e1 = e0 + (d >> 22);
            float a[8];
            #pragma unroll
            for (int j = 0; j < 8; ++j) a[j] = 0.0f;
            for (int e = e0; e < e1; e += 2) {
                int2 qp = *(const int2*)&epkg[e];
                hlf2 xs = *(const hlf2*)&xe[e];
                uint4 g0 = *(const uint4*)(E1b + ((unsigned)qp.x >> 16));
                uint4 g1 = *(const uint4*)(E1b + ((unsigned)qp.y >> 16));
                MAC8(g0, xs[0]); MAC8(g1, xs[1]);
            }
            uint4 ov;
            ov.x = __builtin_bit_cast(unsigned, __builtin_amdgcn_cvt_pkrtz(
                       fmaxf(a[0] + b1v[0], 0.0f), fmaxf(a[1] + b1v[1], 0.0f)));
            ov.y = __builtin_bit_cast(unsigned, __builtin_amdgcn_cvt_pkrtz(
                       fmaxf(a[2] + b1v[2], 0.0f), fmaxf(a[3] + b1v[3], 0.0f)));
            ov.z = __builtin_bit_cast(unsigned, __builtin_amdgcn_cvt_pkrtz(
                       fmaxf(a[4] + b1v[4], 0.0f), fmaxf(a[5] + b1v[5], 0.0f)));
            ov.w = __builtin_bit_cast(unsigned, __builtin_amdgcn_cvt_pkrtz(
                       fmaxf(a[6] + b1v[6], 0.0f), fmaxf(a[7] + b1v[7], 0.0f)));
            *(uint4*)&H[c * HD + dbase] = ov;
        }
    }
    __syncthreads();

    // ---- SpMM2: agg2 = S @ h1 (raw, no bias) -> regs, then swizzled A2 in H
    {
        const char* Hb = (const char*)H + dbase * 2;
        uint4 agg[4]; int cset[4];
        #pragma unroll 1
        for (int set = 0; set < 4; ++set) {
            int r = set * 128 + wave * 8 + grp;
            unsigned d = descg[r];
            int e0 = d & 8191, c = (d >> 13) & 511, e1 = e0 + (d >> 22);
            float a[8];
            #pragma unroll
            for (int j = 0; j < 8; ++j) a[j] = 0.0f;
            for (int e = e0; e < e1; e += 2) {
                int2 qp = *(const int2*)&epkg[e];
                uint4 g0 = *(const uint4*)(Hb + ((unsigned)qp.x >> 16));
                uint4 g1 = *(const uint4*)(Hb + ((unsigned)qp.y >> 16));
                MAC8(g0, __builtin_bit_cast(hlf2, (unsigned)qp.x)[0]);
                MAC8(g1, __builtin_bit_cast(hlf2, (unsigned)qp.y)[0]);
            }
            uint4 ov;
            ov.x = __builtin_bit_cast(unsigned, __builtin_amdgcn_cvt_pkrtz(a[0], a[1]));
            ov.y = __builtin_bit_cast(unsigned, __builtin_amdgcn_cvt_pkrtz(a[2], a[3]));
            ov.z = __builtin_bit_cast(unsigned, __builtin_amdgcn_cvt_pkrtz(a[4], a[5]));
            ov.w = __builtin_bit_cast(unsigned, __builtin_amdgcn_cvt_pkrtz(a[6], a[7]));
            agg[set] = ov; cset[set] = c;
        }
        __syncthreads();           // all h1 gathers done; H reusable as A2
        #pragma unroll
        for (int set = 0; set < 4; ++set) {
            int c = cset[set];
            *(uint4*)((char*)H + c * 128 + ((dbase * 2) ^ ((c & 7) << 4))) = agg[set];
        }
    }
    __syncthreads();

    // ---- MFMA: z2 = A2@W2 + b2; t = relu(z2).W3 -> tv (aux)
    {
        const int mbase = wave * 32;
        const int sw0 = (q * 16) ^ ((l15 & 7) << 4);          // ks=0 byte offset
        const int sw1 = (64 + q * 16) ^ ((l15 & 7) << 4);     // ks=1 byte offset
        const char* rb0 = (const char*)H + (mbase + l15) * 128;
        const char* rb1 = rb0 + 16 * 128;
        hlf8 a00 = *(const hlf8*)(rb0 + sw0), a01 = *(const hlf8*)(rb0 + sw1);
        hlf8 a10 = *(const hlf8*)(rb1 + sw0), a11 = *(const hlf8*)(rb1 + sw1);
        float tp[2][4];
        #pragma unroll
        for (int i = 0; i < 4; ++i) { tp[0][i] = 0.0f; tp[1][i] = 0.0f; }
        #pragma unroll
        for (int nt = 0; nt < 4; ++nt) {
            int col = nt * 16 + l15;
            hlf8 bf0 = *(const hlf8*)&W2T[col * HD + q * 8];
            hlf8 bf1 = *(const hlf8*)&W2T[col * HD + 32 + q * 8];
            f32x4 acc0 = (f32x4){0.f, 0.f, 0.f, 0.f};
            f32x4 acc1 = (f32x4){0.f, 0.f, 0.f, 0.f};
            acc0 = __builtin_amdgcn_mfma_f32_16x16x32_f16(a00, bf0, acc0, 0, 0, 0);
            acc0 = __builtin_amdgcn_mfma_f32_16x16x32_f16(a01, bf1, acc0, 0, 0, 0);
            acc1 = __builtin_amdgcn_mfma_f32_16x16x32_f16(a10, bf0, acc1, 0, 0, 0);
            acc1 = __builtin_amdgcn_mfma_f32_16x16x32_f16(a11, bf1, acc1, 0, 0, 0);
            float bc = b2[col], wc = W3[col];
            #pragma unroll
            for (int i = 0; i < 4; ++i) {
                tp[0][i] += fmaxf(acc0[i] + bc, 0.0f) * wc;
                tp[1][i] += fmaxf(acc1[i] + bc, 0.0f) * wc;
            }
        }
        #pragma unroll
        for (int mt = 0; mt < 2; ++mt)
            #pragma unroll
            for (int i = 0; i < 4; ++i) {
                float v = tp[mt][i];
                v += __shfl_xor(v, 1, 64);
                v += __shfl_xor(v, 2, 64);
                v += __shfl_xor(v, 4, 64);
                v += __shfl_xor(v, 8, 64);
                if (l15 == 0) aux[mbase + mt * 16 + q * 4 + i] = v;  // tv[node]
            }
    }
    __syncthreads();

    // ---- SpMM3: slog[col] = (S @ tv)[col] + b3   (2 threads per rank)
    {
        int rk = t >> 1, hh = t & 1;
        unsigned d = descg[rk];
        int e0 = d & 8191, c = (d >> 13) & 511, deg = d >> 22;
        int mid = e0 + (deg >> 1);
        int ea = hh ? mid : e0;
        int eb = hh ? e0 + deg : mid;
        float acc = 0.0f;
        for (int e = ea; e < eb; ++e) {
            unsigned pe = (unsigned)epkg[e];
            float nf = (float)__builtin_bit_cast(hlf2, pe)[0];
            acc = fmaf(nf, aux[pe >> 23], acc);
        }
        acc += __shfl_xor(acc, 1, 64);
        if (!hh) slog[c] = acc + b3[0];
    }
    __syncthreads();

    // ---- softmax stats over [0, MAIN)
    if (t < 64) {
        float v = (t < MAIN) ? slog[t] : -1e30f;
        float m = v;
        m = fmaxf(m, __shfl_xor(m, 1, 64));
        m = fmaxf(m, __shfl_xor(m, 2, 64));
        m = fmaxf(m, __shfl_xor(m, 4, 64));
        m = fmaxf(m, __shfl_xor(m, 8, 64));
        float ev = (t < MAIN) ? __expf(v - m) : 0.0f;
        ev += __shfl_xor(ev, 1, 64);
        ev += __shfl_xor(ev, 2, 64);
        ev += __shfl_xor(ev, 4, 64);
        ev += __shfl_xor(ev, 8, 64);
        if (t == 0) { sred[0] = m; sred[1] = ev; }
    }
    __syncthreads();

    if (t < NUM) {
        float l = slog[t];
        float o = (t < MAIN) ? __expf(l - sred[0]) / sred[1]
                             : 1.0f / (1.0f + __expf(-l));
        out[b * NUM + t] = o;
    }
#undef MAC8
}

// ---------------------------------------------------------------------------
extern "C" void kernel_launch(void* const* d_in, const int* in_sizes, int n_in,
                              void* d_out, int out_size, void* d_ws, size_t ws_size,
                              hipStream_t stream) {
    const float* x    = (const float*)d_in[0];
    const float* emb  = (const float*)d_in[1];
    const float* W1   = (const float*)d_in[2];
    const float* b1   = (const float*)d_in[3];
    const float* W2   = (const float*)d_in[4];
    const float* b2   = (const float*)d_in[5];
    const float* W3   = (const float*)d_in[6];
    const float* b3   = (const float*)d_in[7];
    const int*   erow = (const int*)d_in[8];
    const int*   ecol = (const int*)d_in[9];

    char* ws = (char*)d_ws;
    unsigned* desc = (unsigned*)ws;          // 512 u32  [0, 2048)
    int*   epk    = (int*)(ws + 4224);       // 4608 ints [4224, 22656)
    short* E1     = (short*)(ws + 22656);    // 32768 f16 [22656, 88192)
    short* W2T    = (short*)(ws + 88192);    // 4096 f16  [88192, 96384)

    prep_all<<<73, 512, 0, stream>>>(erow, ecol, emb, W1, W2,
                                     desc, epk, E1, W2T);
    gcn_body<<<NB, 1024, 0, stream>>>(x, (const hlf*)E1, (const hlf*)W2T,
                                      b1, b2, W3, b3,
                                      desc, epk, (float*)d_out);
}

// Round 4
// 167.965 us; speedup vs baseline: 1.0148x; 1.0148x over previous
//
#include <hip/hip_runtime.h>
#include <stdint.h>

#define NB    1024   // batch
#define NUM   512    // nodes
#define HD    64     // hidden dim
#define NE    4096   // edges
#define NEP   4608   // padded edge capacity (each column padded to even count)
#define MAIN  10     // softmax segment

typedef _Float16 hlf;
typedef __attribute__((ext_vector_type(2))) _Float16 hlf2;
typedef __attribute__((ext_vector_type(8))) _Float16 hlf8;
typedef __attribute__((ext_vector_type(4))) float f32x4;

__device__ __forceinline__ unsigned short f2h(float f) {
    hlf v = (hlf)f;
    return __builtin_bit_cast(unsigned short, v);
}

// ---------------------------------------------------------------------------
// Prep: block 0 builds degree-sorted, even-padded CSR (packed rank
// descriptors desc[r] = e0 | col<<13 | pdeg<<22) via wave-shfl scans;
// blocks 1..72 cast E1 = emb@W1 and W2T = W2^T to f16.
// Edge pack: epk = (row << 23) | f16(norm)  -> row*128 = byte offset in hi16.
// ---------------------------------------------------------------------------
__global__ __launch_bounds__(512) void prep_all(
    const int* __restrict__ erow, const int* __restrict__ ecol,
    const float* __restrict__ emb, const float* __restrict__ W1,
    const float* __restrict__ W2,
    unsigned* __restrict__ desc, int* __restrict__ epk,
    short* __restrict__ E1, short* __restrict__ W2T)
{
    const int t = threadIdx.x;
    if (blockIdx.x != 0) {
        int g = (blockIdx.x - 1) * 512 + t;     // 72 x 512 = 36864
        if (g < NUM * HD) {
            int node = g >> 6, dim = g & 63;
            float acc = 0.0f;
            #pragma unroll
            for (int k = 0; k < HD; ++k) acc += emb[node * HD + k] * W1[k * HD + dim];
            E1[g] = (short)f2h(acc);
        } else if (g < NUM * HD + HD * HD) {
            int j = g - NUM * HD;
            int dout = j >> 6, din = j & 63;
            W2T[j] = (short)f2h(W2[din * HD + dout]);
        }
        return;
    }

    __shared__ int   sdeg[NUM];     // degree -> bin cursor -> edge cursor
    __shared__ int   aux[NUM];      // histogram scan -> rank starts
    __shared__ float sdv[NUM];
    __shared__ int   rnk[NUM];
    __shared__ int   rdg[NUM];      // padded degree by rank
    __shared__ int   scol[NUM];     // original col by rank
    __shared__ int   wsum[8];

    const int lane = t & 63, wv = t >> 6;

    sdeg[t] = 0; aux[t] = 0;
    __syncthreads();
    for (int e = t; e < NE; e += 512) atomicAdd(&sdeg[ecol[e]], 1);
    __syncthreads();
    const int deg  = sdeg[t];
    const int pdeg = (deg + 1) & ~1;            // pad to even
    const int dbin = deg < NUM ? deg : NUM - 1;
    sdv[t] = deg > 0 ? rsqrtf((float)deg) : 0.0f;
    atomicAdd(&aux[dbin], 1);
    __syncthreads();
    // scan histogram (shfl)
    {
        int v = aux[t];
        #pragma unroll
        for (int ofs = 1; ofs < 64; ofs <<= 1) {
            int sh = __shfl_up(v, ofs, 64);
            if (lane >= ofs) v += sh;
        }
        if (lane == 63) wsum[wv] = v;
        __syncthreads();
        if (t == 0) {
            int s = 0;
            #pragma unroll
            for (int w = 0; w < 8; ++w) { int tmp = wsum[w]; wsum[w] = s; s += tmp; }
        }
        __syncthreads();
        int inc = v + wsum[wv];
        aux[t]  = inc;                          // inclusive histogram scan
        __syncthreads();
        sdeg[t] = (t == 0) ? 0 : aux[t - 1];    // bin cursors (exclusive)
        __syncthreads();
    }
    {
        int r = atomicAdd(&sdeg[dbin], 1);      // degree-sorted rank
        rnk[t] = r;
        rdg[r] = pdeg;
        scol[r] = t;
    }
    __syncthreads();
    // scan padded degrees by rank -> rank CSR (all-even offsets) + descriptors
    {
        int dv = rdg[t], v = dv;
        #pragma unroll
        for (int ofs = 1; ofs < 64; ofs <<= 1) {
            int sh = __shfl_up(v, ofs, 64);
            if (lane >= ofs) v += sh;
        }
        if (lane == 63) wsum[wv] = v;
        __syncthreads();
        if (t == 0) {
            int s = 0;
            #pragma unroll
            for (int w = 0; w < 8; ++w) { int tmp = wsum[w]; wsum[w] = s; s += tmp; }
        }
        __syncthreads();
        int inc  = v + wsum[wv];
        int excl = inc - dv;
        desc[t] = (unsigned)excl | ((unsigned)scol[t] << 13) | ((unsigned)dv << 22);
        aux[t] = excl;                          // rank start
        __syncthreads();
    }
    sdeg[t] = aux[rnk[t]];                      // per-ORIGINAL-col edge cursor
    __syncthreads();
    for (int i = t; i < NEP; i += 512) epk[i] = 0;   // zero pads
    __syncthreads();
    for (int e = t; e < NE; e += 512) {
        int c = ecol[e], rr = erow[e];
        int p = atomicAdd(&sdeg[c], 1);
        unsigned ns = (unsigned)f2h(sdv[rr] * sdv[c]);
        epk[p] = (rr << 23) | (int)ns;          // hi16 = row*128 (byte offset)
    }
}

// ---------------------------------------------------------------------------
// Body: one block (1024 thr, 16 waves) per batch element; 2 blocks/CU.
// Uses S@(h@W) = (S@h)@W to defer the dense matmul past the aggregation:
//   SpMM1: h1 = relu(S@(x*E1) + b1)   gather E1 from L2, scale n*x (LDS xe)
//   8-set stripe pipeline: per 64 degree-sorted ranks
//       SpMM2: agg2 = S@h1 -> 8 KB swizzled stripe (overlays xe)
//       MFMA : tv += rowsum(relu(agg2@W2 + b2) * W3)  (atomicAdd into aux)
//   SpMM3: logits = S@tv + b3; softmax/sigmoid
// No register array is held across a barrier -> no spills at the 64-VGPR cap.
// ---------------------------------------------------------------------------
__global__ __launch_bounds__(1024, 8) void gcn_body(
    const float* __restrict__ x, const hlf* __restrict__ E1,
    const hlf* __restrict__ W2T,
    const float* __restrict__ b1, const float* __restrict__ b2,
    const float* __restrict__ W3, const float* __restrict__ b3,
    const unsigned* __restrict__ descg, const int* __restrict__ epkg,
    float* __restrict__ out)
{
    __shared__ hlf   H[NUM * HD];      // 65536 B: h1; slog overlays after last set
    __shared__ hlf   SP[NEP];          // 9216 B: xe (SpMM1) / 64x64 swz stripe (SpMM2+MFMA)
    __shared__ float aux[NUM];         // 2048 B: x, then tv accumulator
    __shared__ float sred[2];

    float* slog = (float*)H;           // overlays H after stripe pipeline

    const int t     = threadIdx.x;
    const int b     = blockIdx.x;
    const int lane  = t & 63;
    const int wave  = t >> 6;          // 0..15
    const int q     = lane >> 4;       // 0..3
    const int l15   = lane & 15;
    const int grp   = lane >> 3;       // 8-lane group id (SpMM1)
    const int dbase = (lane & 7) * 8;  // SpMM1 8-dim strip

    // ---- stage x
    if (t < NUM) aux[t] = x[b * NUM + t];
    __syncthreads();
    // ---- xe = n * x[row] per edge (pads: n=0 -> 0)
    for (int i = t; i < NEP; i += 1024) {
        unsigned pe = (unsigned)epkg[i];
        float nf = (float)__builtin_bit_cast(hlf2, pe)[0];
        SP[i] = (hlf)(nf * aux[pe >> 23]);
    }
    __syncthreads();
    if (t < NUM) aux[t] = 0.0f;        // tv accumulator (visible after SpMM1 barrier)

// 8 f16->f32 mixed FMAs with f16 scale
#define MAC8(hv, sc) {                                                        \
        const hlf2 p0 = __builtin_bit_cast(hlf2, (hv).x);                     \
        const hlf2 p1 = __builtin_bit_cast(hlf2, (hv).y);                     \
        const hlf2 p2 = __builtin_bit_cast(hlf2, (hv).z);                     \
        const hlf2 p3 = __builtin_bit_cast(hlf2, (hv).w);                     \
        a[0] = fmaf((float)p0[0], (float)(sc), a[0]);                         \
        a[1] = fmaf((float)p0[1], (float)(sc), a[1]);                         \
        a[2] = fmaf((float)p1[0], (float)(sc), a[2]);                         \
        a[3] = fmaf((float)p1[1], (float)(sc), a[3]);                         \
        a[4] = fmaf((float)p2[0], (float)(sc), a[4]);                         \
        a[5] = fmaf((float)p2[1], (float)(sc), a[5]);                         \
        a[6] = fmaf((float)p3[0], (float)(sc), a[6]);                         \
        a[7] = fmaf((float)p3[1], (float)(sc), a[7]); }

// 4 f16->f32 mixed FMAs with f16 scale
#define MAC4(hv, sc) {                                                        \
        const hlf2 p0 = __builtin_bit_cast(hlf2, (hv).x);                     \
        const hlf2 p1 = __builtin_bit_cast(hlf2, (hv).y);                     \
        a[0] = fmaf((float)p0[0], (float)(sc), a[0]);                         \
        a[1] = fmaf((float)p0[1], (float)(sc), a[1]);                         \
        a[2] = fmaf((float)p1[0], (float)(sc), a[2]);                         \
        a[3] = fmaf((float)p1[1], (float)(sc), a[3]); }

    // ---- SpMM1: h1 = relu(S @ (x*E1) + b1) -> H[c][d]; gather E1 from L2
    {
        const char* E1b = (const char*)E1 + dbase * 2;
        #pragma unroll 1
        for (int set = 0; set < 4; ++set) {
            int r = set * 128 + wave * 8 + grp;
            unsigned d = descg[r];
            int e0 = d & 8191, c = (d >> 13) & 511, e1 = e0 + (d >> 22);
            float a[8];
            #pragma unroll
            for (int j = 0; j < 8; ++j) a[j] = 0.0f;
            for (int e = e0; e < e1; e += 2) {
                int2 qp = *(const int2*)&epkg[e];
                hlf2 xs = *(const hlf2*)&SP[e];
                uint4 g0 = *(const uint4*)(E1b + ((unsigned)qp.x >> 16));
                uint4 g1 = *(const uint4*)(E1b + ((unsigned)qp.y >> 16));
                MAC8(g0, xs[0]); MAC8(g1, xs[1]);
            }
            f32x4 u0 = *(const f32x4*)&b1[dbase];
            f32x4 u1 = *(const f32x4*)&b1[dbase + 4];
            uint4 ov;
            ov.x = __builtin_bit_cast(unsigned, __builtin_amdgcn_cvt_pkrtz(
                       fmaxf(a[0] + u0[0], 0.0f), fmaxf(a[1] + u0[1], 0.0f)));
            ov.y = __builtin_bit_cast(unsigned, __builtin_amdgcn_cvt_pkrtz(
                       fmaxf(a[2] + u0[2], 0.0f), fmaxf(a[3] + u0[3], 0.0f)));
            ov.z = __builtin_bit_cast(unsigned, __builtin_amdgcn_cvt_pkrtz(
                       fmaxf(a[4] + u1[0], 0.0f), fmaxf(a[5] + u1[1], 0.0f)));
            ov.w = __builtin_bit_cast(unsigned, __builtin_amdgcn_cvt_pkrtz(
                       fmaxf(a[6] + u1[2], 0.0f), fmaxf(a[7] + u1[3], 0.0f)));
            *(uint4*)&H[c * HD + dbase] = ov;
        }
    }
    __syncthreads();

    // ---- stripe pipeline: 8 sets x 64 degree-sorted ranks
    {
        const int g16 = lane >> 4;     // 0..3: rank slot within wave (SpMM2)
        const int j16 = lane & 15;     // 4-dim strip within rank
        const char* Hb2 = (const char*)H + j16 * 8;
        #pragma unroll 1
        for (int s = 0; s < 8; ++s) {
            // SpMM2: agg2 rows -> swizzled stripe
            {
                int lr = wave * 4 + g16;               // 0..63 local rank
                unsigned d = descg[s * 64 + lr];
                int e0 = d & 8191, e1 = e0 + (d >> 22);
                float a[4];
                #pragma unroll
                for (int j = 0; j < 4; ++j) a[j] = 0.0f;
                for (int e = e0; e < e1; e += 2) {
                    int2 qp = *(const int2*)&epkg[e];
                    uint2 g0 = *(const uint2*)(Hb2 + ((unsigned)qp.x >> 16));
                    uint2 g1 = *(const uint2*)(Hb2 + ((unsigned)qp.y >> 16));
                    MAC4(g0, __builtin_bit_cast(hlf2, (unsigned)qp.x)[0]);
                    MAC4(g1, __builtin_bit_cast(hlf2, (unsigned)qp.y)[0]);
                }
                uint2 ov;
                ov.x = __builtin_bit_cast(unsigned,
                           __builtin_amdgcn_cvt_pkrtz(a[0], a[1]));
                ov.y = __builtin_bit_cast(unsigned,
                           __builtin_amdgcn_cvt_pkrtz(a[2], a[3]));
                *(uint2*)((char*)SP + lr * 128 + ((j16 * 8) ^ ((lr & 7) << 4))) = ov;
            }
            __syncthreads();
            // MFMA: 16 waves = 4 row-tiles x 4 col-tiles over the 64x64 stripe
            {
                int rt = wave >> 2, ct = wave & 3;
                int lrr = rt * 16 + l15;
                const char* rb = (const char*)SP + lrr * 128;
                int sw = (l15 & 7) << 4;
                hlf8 a0 = *(const hlf8*)(rb + ((q * 16) ^ sw));
                hlf8 a1 = *(const hlf8*)(rb + ((64 + q * 16) ^ sw));
                int col = ct * 16 + l15;
                hlf8 bf0 = *(const hlf8*)&W2T[col * HD + q * 8];
                hlf8 bf1 = *(const hlf8*)&W2T[col * HD + 32 + q * 8];
                f32x4 acc = (f32x4){0.f, 0.f, 0.f, 0.f};
                acc = __builtin_amdgcn_mfma_f32_16x16x32_f16(a0, bf0, acc, 0, 0, 0);
                acc = __builtin_amdgcn_mfma_f32_16x16x32_f16(a1, bf1, acc, 0, 0, 0);
                float bc = b2[col], wc = W3[col];
                #pragma unroll
                for (int i = 0; i < 4; ++i) {
                    float v = fmaxf(acc[i] + bc, 0.0f) * wc;
                    v += __shfl_xor(v, 1, 64);
                    v += __shfl_xor(v, 2, 64);
                    v += __shfl_xor(v, 4, 64);
                    v += __shfl_xor(v, 8, 64);
                    if (l15 == 0) {
                        int node = (descg[s * 64 + rt * 16 + q * 4 + i] >> 13) & 511;
                        atomicAdd(&aux[node], v);
                    }
                }
            }
            __syncthreads();
        }
    }

    // ---- SpMM3: slog[col] = (S @ tv)[col] + b3   (2 threads per rank)
    {
        int rk = t >> 1, hh = t & 1;
        unsigned d = descg[rk];
        int e0 = d & 8191, c = (d >> 13) & 511, deg = d >> 22;
        int mid = e0 + (deg >> 1);
        int ea = hh ? mid : e0;
        int eb = hh ? e0 + deg : mid;
        float acc = 0.0f;
        for (int e = ea; e < eb; ++e) {
            unsigned pe = (unsigned)epkg[e];
            float nf = (float)__builtin_bit_cast(hlf2, pe)[0];
            acc = fmaf(nf, aux[pe >> 23], acc);
        }
        acc += __shfl_xor(acc, 1, 64);
        if (!hh) slog[c] = acc + b3[0];
    }
    __syncthreads();

    // ---- softmax stats over [0, MAIN)
    if (t < 64) {
        float v = (t < MAIN) ? slog[t] : -1e30f;
        float m = v;
        m = fmaxf(m, __shfl_xor(m, 1, 64));
        m = fmaxf(m, __shfl_xor(m, 2, 64));
        m = fmaxf(m, __shfl_xor(m, 4, 64));
        m = fmaxf(m, __shfl_xor(m, 8, 64));
        float ev = (t < MAIN) ? __expf(v - m) : 0.0f;
        ev += __shfl_xor(ev, 1, 64);
        ev += __shfl_xor(ev, 2, 64);
        ev += __shfl_xor(ev, 4, 64);
        ev += __shfl_xor(ev, 8, 64);
        if (t == 0) { sred[0] = m; sred[1] = ev; }
    }
    __syncthreads();

    if (t < NUM) {
        float l = slog[t];
        float o = (t < MAIN) ? __expf(l - sred[0]) / sred[1]
                             : 1.0f / (1.0f + __expf(-l));
        out[b * NUM + t] = o;
    }
#undef MAC8
#undef MAC4
}

// ---------------------------------------------------------------------------
extern "C" void kernel_launch(void* const* d_in, const int* in_sizes, int n_in,
                              void* d_out, int out_size, void* d_ws, size_t ws_size,
                              hipStream_t stream) {
    const float* x    = (const float*)d_in[0];
    const float* emb  = (const float*)d_in[1];
    const float* W1   = (const float*)d_in[2];
    const float* b1   = (const float*)d_in[3];
    const float* W2   = (const float*)d_in[4];
    const float* b2   = (const float*)d_in[5];
    const float* W3   = (const float*)d_in[6];
    const float* b3   = (const float*)d_in[7];
    const int*   erow = (const int*)d_in[8];
    const int*   ecol = (const int*)d_in[9];

    char* ws = (char*)d_ws;
    unsigned* desc = (unsigned*)ws;          // 512 u32  [0, 2048)
    int*   epk    = (int*)(ws + 4224);       // 4608 ints [4224, 22656)
    short* E1     = (short*)(ws + 22656);    // 32768 f16 [22656, 88192)
    short* W2T    = (short*)(ws + 88192);    // 4096 f16  [88192, 96384)

    prep_all<<<73, 512, 0, stream>>>(erow, ecol, emb, W1, W2,
                                     desc, epk, E1, W2T);
    gcn_body<<<NB, 1024, 0, stream>>>(x, (const hlf*)E1, (const hlf*)W2T,
                                      b1, b2, W3, b3,
                                      desc, epk, (float*)d_out);
}

// Round 6
// 154.732 us; speedup vs baseline: 1.1016x; 1.0855x over previous
//
#include <hip/hip_runtime.h>
#include <stdint.h>

#define NB    1024   // batch
#define NUM   512    // nodes
#define HD    64     // hidden dim
#define NE    4096   // edges
#define NEP   4608   // padded edge capacity (each column padded to even count)
#define MAIN  10     // softmax segment
#define HBS   72     // HB row stride (halfs): 144 B, 16B-aligned b128 slots

typedef _Float16 hlf;
typedef __attribute__((ext_vector_type(2))) _Float16 hlf2;
typedef __attribute__((ext_vector_type(8))) _Float16 hlf8;
typedef __attribute__((ext_vector_type(4))) float f32x4;

__device__ __forceinline__ unsigned short f2h(float f) {
    hlf v = (hlf)f;
    return __builtin_bit_cast(unsigned short, v);
}

// ---------------------------------------------------------------------------
// Prep: block 0 builds degree-sorted, even-padded CSR via wave-shfl scans;
// blocks 1..72 cast E1 = emb@W1 and W2T = W2^T to f16.
// Edge pack: epk = (row << 23) | f16(norm)  -> row*128 = byte offset in hi16.
// ---------------------------------------------------------------------------
__global__ __launch_bounds__(512) void prep_all(
    const int* __restrict__ erow, const int* __restrict__ ecol,
    const float* __restrict__ emb, const float* __restrict__ W1,
    const float* __restrict__ W2,
    int* __restrict__ rsptr, int* __restrict__ colmap, int* __restrict__ epk,
    short* __restrict__ E1, short* __restrict__ W2T)
{
    const int t = threadIdx.x;
    if (blockIdx.x != 0) {
        int g = (blockIdx.x - 1) * 512 + t;     // 72 x 512 = 36864
        if (g < NUM * HD) {
            int node = g >> 6, dim = g & 63;
            float acc = 0.0f;
            #pragma unroll
            for (int k = 0; k < HD; ++k) acc += emb[node * HD + k] * W1[k * HD + dim];
            E1[g] = (short)f2h(acc);
        } else if (g < NUM * HD + HD * HD) {
            int j = g - NUM * HD;
            int dout = j >> 6, din = j & 63;
            W2T[j] = (short)f2h(W2[din * HD + dout]);
        }
        return;
    }

    __shared__ int   sdeg[NUM];     // degree -> bin cursor -> edge cursor
    __shared__ int   aux[NUM];      // histogram scan -> rank starts
    __shared__ float sdv[NUM];
    __shared__ int   rnk[NUM];
    __shared__ int   rdg[NUM];      // padded degree by rank
    __shared__ int   wsum[8];

    const int lane = t & 63, wv = t >> 6;

    sdeg[t] = 0; aux[t] = 0;
    __syncthreads();
    for (int e = t; e < NE; e += 512) atomicAdd(&sdeg[ecol[e]], 1);
    __syncthreads();
    const int deg  = sdeg[t];
    const int pdeg = (deg + 1) & ~1;            // pad to even
    const int dbin = deg < NUM ? deg : NUM - 1;
    sdv[t] = deg > 0 ? rsqrtf((float)deg) : 0.0f;
    atomicAdd(&aux[dbin], 1);
    __syncthreads();
    // scan histogram (shfl)
    {
        int v = aux[t];
        #pragma unroll
        for (int ofs = 1; ofs < 64; ofs <<= 1) {
            int sh = __shfl_up(v, ofs, 64);
            if (lane >= ofs) v += sh;
        }
        if (lane == 63) wsum[wv] = v;
        __syncthreads();
        if (t == 0) {
            int s = 0;
            #pragma unroll
            for (int w = 0; w < 8; ++w) { int tmp = wsum[w]; wsum[w] = s; s += tmp; }
        }
        __syncthreads();
        int inc = v + wsum[wv];
        aux[t]  = inc;                          // inclusive histogram scan
        __syncthreads();
        sdeg[t] = (t == 0) ? 0 : aux[t - 1];    // bin cursors (exclusive)
        __syncthreads();
    }
    {
        int r = atomicAdd(&sdeg[dbin], 1);      // degree-sorted rank
        rnk[t] = r;
        rdg[r] = pdeg;
        colmap[r] = t;
    }
    __syncthreads();
    // scan padded degrees by rank -> rank CSR (all-even offsets)
    {
        int dv = rdg[t], v = dv;
        #pragma unroll
        for (int ofs = 1; ofs < 64; ofs <<= 1) {
            int sh = __shfl_up(v, ofs, 64);
            if (lane >= ofs) v += sh;
        }
        if (lane == 63) wsum[wv] = v;
        __syncthreads();
        if (t == 0) {
            int s = 0;
            #pragma unroll
            for (int w = 0; w < 8; ++w) { int tmp = wsum[w]; wsum[w] = s; s += tmp; }
        }
        __syncthreads();
        int inc  = v + wsum[wv];
        int excl = inc - dv;
        rsptr[t] = excl;
        if (t == NUM - 1) rsptr[NUM] = inc;
        aux[t] = excl;                          // rank start
        __syncthreads();
    }
    sdeg[t] = aux[rnk[t]];                      // per-ORIGINAL-col edge cursor
    __syncthreads();
    for (int i = t; i < NEP; i += 512) epk[i] = 0;   // zero pads
    __syncthreads();
    for (int e = t; e < NE; e += 512) {
        int c = ecol[e], rr = erow[e];
        int p = atomicAdd(&sdeg[c], 1);
        unsigned ns = (unsigned)f2h(sdv[rr] * sdv[c]);
        epk[p] = (rr << 23) | (int)ns;          // hi16 = row*128 (byte offset)
    }
}

// ---------------------------------------------------------------------------
// Body: one block (1024 thr, 16 waves) per batch element.
// SpMM loops process TWO ranks (r, r+128) per 8-lane group concurrently:
// two independent dep-chains -> 8 ds_read_b128 in flight per wave.
// ---------------------------------------------------------------------------
__global__ __launch_bounds__(1024, 4) void gcn_body(
    const float* __restrict__ x, const hlf* __restrict__ E1,
    const hlf* __restrict__ W2T,
    const float* __restrict__ b1, const float* __restrict__ b2,
    const float* __restrict__ W3, const float* __restrict__ b3,
    const int* __restrict__ rsptrg, const int* __restrict__ colmap,
    const int* __restrict__ epkg,
    float* __restrict__ out)
{
    __shared__ hlf HA[NUM * HD];       // 65536 B [node][64] (B1, later g = h1@W2)
    __shared__ hlf HB[NUM * HBS];      // 73728 B [node][72] (h1); overlays tv/slog
    __shared__ int eps[NEP];           // 18432 B packed padded edges
    __shared__ int sptr[513];
    __shared__ float sred[2];

    float* tv   = (float*)HB;          // 512 floats (after MFMA, HB dead)
    float* slog = ((float*)HB) + NUM;

    const int t     = threadIdx.x;
    const int b     = blockIdx.x;
    const int lane  = t & 63;
    const int wave  = t >> 6;          // 0..15
    const int q     = lane >> 4;
    const int l15   = lane & 15;
    const int grp   = lane >> 3;       // column slot within wave
    const int dbase = (lane & 7) * 8;  // this lane's 8-dim strip

    // ---- stage edges + csr
    {
        const int4* g4 = (const int4*)epkg;
        *(int4*)&eps[t * 4] = g4[t];                       // 4096 ints
        if (t < 128) *(int4*)&eps[4096 + t * 4] = g4[1024 + t];
    }
    if (t < 513) sptr[t] = rsptrg[t];

    // ---- build HA = B1: B1[r][d] = x[b,r] * E1[r][d]   (f16 storage)
    #pragma unroll
    for (int p = 0; p < 4; ++p) {
        int i = t + p * 1024;
        int r = i >> 3, d8 = (i & 7) * 8;
        float xr = x[b * NUM + r];
        hlf  xh = (hlf)xr;
        hlf8 e  = *(const hlf8*)&E1[r * HD + d8];
        hlf8 o;
        #pragma unroll
        for (int j = 0; j < 8; ++j) o[j] = e[j] * xh;
        *(hlf8*)&HA[r * HD + d8] = o;
    }

    // per-lane bias/weight strips
    float b1v[8], b2v[8], w3v[8];
    {
        f32x4 u0 = *(const f32x4*)&b1[dbase], u1 = *(const f32x4*)&b1[dbase + 4];
        f32x4 v0 = *(const f32x4*)&b2[dbase], v1 = *(const f32x4*)&b2[dbase + 4];
        f32x4 w0 = *(const f32x4*)&W3[dbase], w1 = *(const f32x4*)&W3[dbase + 4];
        #pragma unroll
        for (int j = 0; j < 4; ++j) {
            b1v[j] = u0[j]; b1v[j + 4] = u1[j];
            b2v[j] = v0[j]; b2v[j + 4] = v1[j];
            w3v[j] = w0[j]; w3v[j + 4] = w1[j];
        }
    }
    const char* HAb = (const char*)HA + dbase * 2;   // per-lane base
    __syncthreads();

// load one gathered row (hi16 of pe is already a byte offset)
#define LDROW(d, pe) d = *(const uint4*)(HAb + ((unsigned)(pe) >> 16));
// 8 f16->f32 mixed FMAs into named acc; norm is the low f16 half of pe
#define MACROW(acc, hv, pe) {                                                 \
        const hlf nh = __builtin_bit_cast(hlf2, (unsigned)(pe))[0];           \
        const hlf2 p0 = __builtin_bit_cast(hlf2, (hv).x);                     \
        const hlf2 p1 = __builtin_bit_cast(hlf2, (hv).y);                     \
        const hlf2 p2 = __builtin_bit_cast(hlf2, (hv).z);                     \
        const hlf2 p3 = __builtin_bit_cast(hlf2, (hv).w);                     \
        acc[0] = fmaf((float)p0[0], (float)nh, acc[0]);                       \
        acc[1] = fmaf((float)p0[1], (float)nh, acc[1]);                       \
        acc[2] = fmaf((float)p1[0], (float)nh, acc[2]);                       \
        acc[3] = fmaf((float)p1[1], (float)nh, acc[3]);                       \
        acc[4] = fmaf((float)p2[0], (float)nh, acc[4]);                       \
        acc[5] = fmaf((float)p2[1], (float)nh, acc[5]);                       \
        acc[6] = fmaf((float)p3[0], (float)nh, acc[6]);                       \
        acc[7] = fmaf((float)p3[1], (float)nh, acc[7]); }

// 4-edge chunk into one acc
#define CHUNK4(acc, e) {                                                      \
        int2 qa = *(const int2*)&eps[e];  int2 qb = *(const int2*)&eps[(e)+2];\
        uint4 c0, c1, c2, c3;                                                 \
        LDROW(c0, qa.x) LDROW(c1, qa.y) LDROW(c2, qb.x) LDROW(c3, qb.y)       \
        MACROW(acc, c0, qa.x) MACROW(acc, c1, qa.y)                           \
        MACROW(acc, c2, qb.x) MACROW(acc, c3, qb.y) }
// 2-edge tail into one acc
#define CHUNK2(acc, e) {                                                      \
        int2 qa = *(const int2*)&eps[e];                                      \
        uint4 c0, c1;                                                         \
        LDROW(c0, qa.x) LDROW(c1, qa.y)                                       \
        MACROW(acc, c0, qa.x) MACROW(acc, c1, qa.y) }

    // ---- SpMM1: h1 = relu(S @ B1 + b1) -> HB[c][d]
    // dual-rank interleave: ranks rA, rB=rA+128 jointly -> 8 gathers in flight
    #pragma unroll 1
    for (int p = 0; p < 2; ++p) {
        int rA = p * 256 + wave * 8 + grp;
        int rB = rA + 128;
        int eA = sptr[rA], eA1 = sptr[rA + 1];
        int eB = sptr[rB], eB1 = sptr[rB + 1];
        int cA = colmap[rA], cB = colmap[rB];
        float a0[8], a1[8];
        #pragma unroll
        for (int j = 0; j < 8; ++j) { a0[j] = 0.0f; a1[j] = 0.0f; }
        while (eA + 4 <= eA1 && eB + 4 <= eB1) {
            int2 qa = *(const int2*)&eps[eA];
            int2 qb = *(const int2*)&eps[eA + 2];
            int2 qc = *(const int2*)&eps[eB];
            int2 qd = *(const int2*)&eps[eB + 2];
            uint4 u0, u1, u2, u3, v0, v1, v2, v3;
            LDROW(u0, qa.x) LDROW(u1, qa.y) LDROW(u2, qb.x) LDROW(u3, qb.y)
            LDROW(v0, qc.x) LDROW(v1, qc.y) LDROW(v2, qd.x) LDROW(v3, qd.y)
            MACROW(a0, u0, qa.x) MACROW(a0, u1, qa.y)
            MACROW(a0, u2, qb.x) MACROW(a0, u3, qb.y)
            MACROW(a1, v0, qc.x) MACROW(a1, v1, qc.y)
            MACROW(a1, v2, qd.x) MACROW(a1, v3, qd.y)
            eA += 4; eB += 4;
        }
        for (; eA + 4 <= eA1; eA += 4) CHUNK4(a0, eA)
        if (eA < eA1) CHUNK2(a0, eA)
        for (; eB + 4 <= eB1; eB += 4) CHUNK4(a1, eB)
        if (eB < eB1) CHUNK2(a1, eB)
        uint4 ov;
        ov.x = __builtin_bit_cast(unsigned, __builtin_amdgcn_cvt_pkrtz(
                   fmaxf(a0[0] + b1v[0], 0.0f), fmaxf(a0[1] + b1v[1], 0.0f)));
        ov.y = __builtin_bit_cast(unsigned, __builtin_amdgcn_cvt_pkrtz(
                   fmaxf(a0[2] + b1v[2], 0.0f), fmaxf(a0[3] + b1v[3], 0.0f)));
        ov.z = __builtin_bit_cast(unsigned, __builtin_amdgcn_cvt_pkrtz(
                   fmaxf(a0[4] + b1v[4], 0.0f), fmaxf(a0[5] + b1v[5], 0.0f)));
        ov.w = __builtin_bit_cast(unsigned, __builtin_amdgcn_cvt_pkrtz(
                   fmaxf(a0[6] + b1v[6], 0.0f), fmaxf(a0[7] + b1v[7], 0.0f)));
        *(uint4*)&HB[cA * HBS + dbase] = ov;
        ov.x = __builtin_bit_cast(unsigned, __builtin_amdgcn_cvt_pkrtz(
                   fmaxf(a1[0] + b1v[0], 0.0f), fmaxf(a1[1] + b1v[1], 0.0f)));
        ov.y = __builtin_bit_cast(unsigned, __builtin_amdgcn_cvt_pkrtz(
                   fmaxf(a1[2] + b1v[2], 0.0f), fmaxf(a1[3] + b1v[3], 0.0f)));
        ov.z = __builtin_bit_cast(unsigned, __builtin_amdgcn_cvt_pkrtz(
                   fmaxf(a1[4] + b1v[4], 0.0f), fmaxf(a1[5] + b1v[5], 0.0f)));
        ov.w = __builtin_bit_cast(unsigned, __builtin_amdgcn_cvt_pkrtz(
                   fmaxf(a1[6] + b1v[6], 0.0f), fmaxf(a1[7] + b1v[7], 0.0f)));
        *(uint4*)&HB[cB * HBS + dbase] = ov;
    }
    __syncthreads();

    // ---- MFMA: g = h1 @ W2 -> HA[node][dout]  (f16 MFMA)
    {
        hlf8 bfr[2][4];
        #pragma unroll
        for (int ks = 0; ks < 2; ++ks)
            #pragma unroll
            for (int nt = 0; nt < 4; ++nt)
                bfr[ks][nt] = *(const hlf8*)&W2T[(nt * 16 + l15) * HD + ks * 32 + q * 8];
        f32x4 acc[2][4];
        #pragma unroll
        for (int mt = 0; mt < 2; ++mt)
            #pragma unroll
            for (int nt = 0; nt < 4; ++nt) acc[mt][nt] = (f32x4){0.f, 0.f, 0.f, 0.f};
        const int mbase = wave * 32;
        #pragma unroll
        for (int mt = 0; mt < 2; ++mt)
            #pragma unroll
            for (int ks = 0; ks < 2; ++ks) {
                hlf8 af = *(const hlf8*)&HB[(mbase + mt * 16 + l15) * HBS
                                            + ks * 32 + q * 8];
                #pragma unroll
                for (int nt = 0; nt < 4; ++nt)
                    acc[mt][nt] = __builtin_amdgcn_mfma_f32_16x16x32_f16(
                        af, bfr[ks][nt], acc[mt][nt], 0, 0, 0);
            }
        #pragma unroll
        for (int mt = 0; mt < 2; ++mt)
            #pragma unroll
            for (int nt = 0; nt < 4; ++nt)
                #pragma unroll
                for (int i = 0; i < 4; ++i)
                    HA[(mbase + mt * 16 + q * 4 + i) * HD + nt * 16 + l15] =
                        (hlf)acc[mt][nt][i];
    }
    __syncthreads();

    // ---- SpMM2 + fused epilogue: tv[c] = sum_d relu((S@g)[c,d] + b2[d]) * W3[d]
    #pragma unroll 1
    for (int p = 0; p < 2; ++p) {
        int rA = p * 256 + wave * 8 + grp;
        int rB = rA + 128;
        int eA = sptr[rA], eA1 = sptr[rA + 1];
        int eB = sptr[rB], eB1 = sptr[rB + 1];
        int cA = colmap[rA], cB = colmap[rB];
        float a0[8], a1[8];
        #pragma unroll
        for (int j = 0; j < 8; ++j) { a0[j] = 0.0f; a1[j] = 0.0f; }
        while (eA + 4 <= eA1 && eB + 4 <= eB1) {
            int2 qa = *(const int2*)&eps[eA];
            int2 qb = *(const int2*)&eps[eA + 2];
            int2 qc = *(const int2*)&eps[eB];
            int2 qd = *(const int2*)&eps[eB + 2];
            uint4 u0, u1, u2, u3, v0, v1, v2, v3;
            LDROW(u0, qa.x) LDROW(u1, qa.y) LDROW(u2, qb.x) LDROW(u3, qb.y)
            LDROW(v0, qc.x) LDROW(v1, qc.y) LDROW(v2, qd.x) LDROW(v3, qd.y)
            MACROW(a0, u0, qa.x) MACROW(a0, u1, qa.y)
            MACROW(a0, u2, qb.x) MACROW(a0, u3, qb.y)
            MACROW(a1, v0, qc.x) MACROW(a1, v1, qc.y)
            MACROW(a1, v2, qd.x) MACROW(a1, v3, qd.y)
            eA += 4; eB += 4;
        }
        for (; eA + 4 <= eA1; eA += 4) CHUNK4(a0, eA)
        if (eA < eA1) CHUNK2(a0, eA)
        for (; eB + 4 <= eB1; eB += 4) CHUNK4(a1, eB)
        if (eB < eB1) CHUNK2(a1, eB)
        float v0s = 0.0f, v1s = 0.0f;
        #pragma unroll
        for (int j = 0; j < 8; ++j) {
            v0s += fmaxf(a0[j] + b2v[j], 0.0f) * w3v[j];
            v1s += fmaxf(a1[j] + b2v[j], 0.0f) * w3v[j];
        }
        v0s += __shfl_xor(v0s, 1, 64);
        v0s += __shfl_xor(v0s, 2, 64);
        v0s += __shfl_xor(v0s, 4, 64);
        v1s += __shfl_xor(v1s, 1, 64);
        v1s += __shfl_xor(v1s, 2, 64);
        v1s += __shfl_xor(v1s, 4, 64);
        if ((lane & 7) == 0) { tv[cA] = v0s; tv[cB] = v1s; }
    }
    __syncthreads();

    // ---- SpMM3: slog[col] = (S @ tv)[col] + b3   (2 threads per rank)
    {
        int rk = t >> 1, hh = t & 1;
        int e0 = sptr[rk], e1 = sptr[rk + 1];
        int mid = (e0 + e1) >> 1;
        int ea = hh ? mid : e0;
        int eb = hh ? e1 : mid;
        float acc = 0.0f;
        for (int e = ea; e < eb; ++e) {
            unsigned pe = (unsigned)eps[e];
            float nf = (float)__builtin_bit_cast(hlf2, pe)[0];
            acc = fmaf(nf, *(const float*)((const char*)tv + (pe >> 21)), acc);
        }
        acc += __shfl_xor(acc, 1, 64);
        if (!hh) slog[colmap[rk]] = acc + b3[0];
    }
    __syncthreads();

    // ---- softmax stats over [0, MAIN)
    if (t < 64) {
        float v = (t < MAIN) ? slog[t] : -1e30f;
        float m = v;
        m = fmaxf(m, __shfl_xor(m, 1, 64));
        m = fmaxf(m, __shfl_xor(m, 2, 64));
        m = fmaxf(m, __shfl_xor(m, 4, 64));
        m = fmaxf(m, __shfl_xor(m, 8, 64));
        float ev = (t < MAIN) ? __expf(v - m) : 0.0f;
        ev += __shfl_xor(ev, 1, 64);
        ev += __shfl_xor(ev, 2, 64);
        ev += __shfl_xor(ev, 4, 64);
        ev += __shfl_xor(ev, 8, 64);
        if (t == 0) { sred[0] = m; sred[1] = ev; }
    }
    __syncthreads();

    if (t < NUM) {
        float l = slog[t];
        float o = (t < MAIN) ? __expf(l - sred[0]) / sred[1]
                             : 1.0f / (1.0f + __expf(-l));
        out[b * NUM + t] = o;
    }
#undef LDROW
#undef MACROW
#undef CHUNK4
#undef CHUNK2
}

// ---------------------------------------------------------------------------
extern "C" void kernel_launch(void* const* d_in, const int* in_sizes, int n_in,
                              void* d_out, int out_size, void* d_ws, size_t ws_size,
                              hipStream_t stream) {
    const float* x    = (const float*)d_in[0];
    const float* emb  = (const float*)d_in[1];
    const float* W1   = (const float*)d_in[2];
    const float* b1   = (const float*)d_in[3];
    const float* W2   = (const float*)d_in[4];
    const float* b2   = (const float*)d_in[5];
    const float* W3   = (const float*)d_in[6];
    const float* b3   = (const float*)d_in[7];
    const int*   erow = (const int*)d_in[8];
    const int*   ecol = (const int*)d_in[9];

    char* ws = (char*)d_ws;
    int*   rsptr  = (int*)ws;                // 513 ints  [0, 2052)
    int*   colmap = (int*)(ws + 2176);       // 512 ints  [2176, 4224)
    int*   epk    = (int*)(ws + 4224);       // 4608 ints [4224, 22656)
    short* E1     = (short*)(ws + 22656);    // 32768 f16 [22656, 88192)
    short* W2T    = (short*)(ws + 88192);    // 4096 f16  [88192, 96384)

    prep_all<<<73, 512, 0, stream>>>(erow, ecol, emb, W1, W2,
                                     rsptr, colmap, epk, E1, W2T);
    gcn_body<<<NB, 1024, 0, stream>>>(x, (const hlf*)E1, (const hlf*)W2T,
                                      b1, b2, W3, b3,
                                      rsptr, colmap, epk, (float*)d_out);
}